// Round 12
// baseline (760.986 us; speedup 1.0000x reference)
//
#include <hip/hip_runtime.h>

// Joiner: out[b,t,u,v] = relu(src[b,t,:]+tgt[b,u,:]) . W[v,:] + bias[v]
// B=4 T=256 U=128 D=512 V=1024.  M = B*T*U = 131072, K=512, N=1024.
// Plan: pass1 materialize act (bf16, 134MB in ws) + Wb (bf16, 1MB in ws),
//       pass2 m97-style 128x128 MFMA GEMM with global_load_lds staging.

typedef __attribute__((ext_vector_type(4))) float f32x4;
typedef __attribute__((ext_vector_type(8))) __bf16 bf16x8;
typedef __attribute__((ext_vector_type(8))) unsigned short u16x8;

#define BM 128
#define BN 128
#define BK 64
#define KDIM 512
#define VDIM 1024
#define MROWS 131072          // B*T*U
#define OUT_MAIN 134217728ull // MROWS * VDIM

__device__ __forceinline__ unsigned short f2bf(float f) {
    unsigned u = __float_as_uint(f);
    unsigned r = 0x7fffu + ((u >> 16) & 1u);   // round-to-nearest-even
    return (unsigned short)((u + r) >> 16);
}

// ---- pass 1a: act[m][k] = bf16(relu(src[bt][k] + tgt[b*U+u][k])) ----
// 67,108,864 elements, 8 per thread -> 8,388,608 threads -> 32768 blocks x 256
__global__ __launch_bounds__(256) void prep_act(const float* __restrict__ src,
                                                const float* __restrict__ tgt,
                                                unsigned short* __restrict__ act) {
    int idx = blockIdx.x * 256 + threadIdx.x;   // 0 .. 8388607
    int m   = idx >> 6;                         // row (b*T+t)*U + u
    int kk  = (idx & 63) << 3;                  // col start (8 elems)
    int u   = m & 127;                          // U = 128
    int bt  = m >> 7;                           // b*T + t
    int b   = bt >> 8;                          // T = 256
    const float* sp = src + ((size_t)bt << 9) + kk;
    const float* tp = tgt + ((((size_t)b << 7) + u) << 9) + kk;
    f32x4 s0 = *(const f32x4*)sp;
    f32x4 s1 = *(const f32x4*)(sp + 4);
    f32x4 t0 = *(const f32x4*)tp;
    f32x4 t1 = *(const f32x4*)(tp + 4);
    u16x8 r;
#pragma unroll
    for (int j = 0; j < 4; j++) {
        float a = s0[j] + t0[j]; a = a > 0.f ? a : 0.f;
        float c = s1[j] + t1[j]; c = c > 0.f ? c : 0.f;
        r[j]     = f2bf(a);
        r[j + 4] = f2bf(c);
    }
    *(u16x8*)(act + ((size_t)m << 9) + kk) = r;
}

// ---- pass 1b: Wb = bf16(W), plus lengths -> out tail as floats ----
// 524288 elements, 8 per thread -> 65536 threads -> 256 blocks x 256
__global__ __launch_bounds__(256) void prep_w(const float* __restrict__ W,
                                              unsigned short* __restrict__ Wb,
                                              const int* __restrict__ slen,
                                              const int* __restrict__ tlen,
                                              float* __restrict__ tail) {
    int idx = blockIdx.x * 256 + threadIdx.x;   // 0..65535
    const float* wp = W + ((size_t)idx << 3);
    f32x4 w0 = *(const f32x4*)wp;
    f32x4 w1 = *(const f32x4*)(wp + 4);
    u16x8 r;
#pragma unroll
    for (int j = 0; j < 4; j++) { r[j] = f2bf(w0[j]); r[j + 4] = f2bf(w1[j]); }
    *(u16x8*)(Wb + ((size_t)idx << 3)) = r;
    if (idx < 4)      tail[idx] = (float)slen[idx];
    else if (idx < 8) tail[idx] = (float)tlen[idx - 4];
}

// ---- pass 2: C[m][n] = act[m][:] . Wb[n][:] + bias[n]  (both K-contiguous) ----
// 128x128 tile, BK=64, 4 waves (2x2), each wave 64x64 via 4x4 frags of 16x16x32.
__global__ __launch_bounds__(256) void gemm_bf16(const unsigned short* __restrict__ A,
                                                 const unsigned short* __restrict__ Bw,
                                                 const float* __restrict__ bias,
                                                 float* __restrict__ out) {
    __shared__ __align__(16) unsigned short As[BM * BK];
    __shared__ __align__(16) unsigned short Bs[BN * BK];

    const int tid  = threadIdx.x;
    const int bid  = blockIdx.x;
    const int mt   = bid >> 3;       // 1024 M-tiles
    const int nt   = bid & 7;        // 8 N-tiles (consecutive blocks share M-tile -> L2)
    const int m0   = mt * BM;
    const int n0   = nt * BN;

    const int lane = tid & 63;
    const int wid  = tid >> 6;
    const int wr   = wid >> 1;       // 0..1
    const int wc   = wid & 1;        // 0..1

    // staging: thread tid loads 16B; LDS dest = base + tid*16 (linear, wave-uniform+lane*16)
    const int srow = tid >> 3;           // 0..31 (+32 per iter)
    const int scol = (tid & 7) * 8;      // bf16 elems

    f32x4 acc[4][4];
#pragma unroll
    for (int i = 0; i < 4; i++)
#pragma unroll
        for (int j = 0; j < 4; j++) acc[i][j] = (f32x4)0.f;

    const unsigned short* Ag = A  + (size_t)m0 * KDIM + scol;
    const unsigned short* Bg = Bw + (size_t)n0 * KDIM + scol;

    for (int k0 = 0; k0 < KDIM; k0 += BK) {
#pragma unroll
        for (int i = 0; i < 4; i++) {
            int r = srow + i * 32;
            __builtin_amdgcn_global_load_lds(
                (const __attribute__((address_space(1))) void*)(Ag + (size_t)r * KDIM + k0),
                (__attribute__((address_space(3))) void*)(&As[r * BK + scol]), 16, 0, 0);
        }
#pragma unroll
        for (int i = 0; i < 4; i++) {
            int r = srow + i * 32;
            __builtin_amdgcn_global_load_lds(
                (const __attribute__((address_space(1))) void*)(Bg + (size_t)r * KDIM + k0),
                (__attribute__((address_space(3))) void*)(&Bs[r * BK + scol]), 16, 0, 0);
        }
        __syncthreads();   // drains vmcnt before any wave reads LDS

#pragma unroll
        for (int kk = 0; kk < 2; kk++) {
            bf16x8 af[4], bf[4];
            const int klo = kk * 32 + (lane >> 4) * 8;
#pragma unroll
            for (int mi = 0; mi < 4; mi++) {
                int row = wr * 64 + mi * 16 + (lane & 15);
                af[mi] = *(const bf16x8*)&As[row * BK + klo];
            }
#pragma unroll
            for (int ni = 0; ni < 4; ni++) {
                int col = wc * 64 + ni * 16 + (lane & 15);
                bf[ni] = *(const bf16x8*)&Bs[col * BK + klo];
            }
#pragma unroll
            for (int mi = 0; mi < 4; mi++)
#pragma unroll
                for (int ni = 0; ni < 4; ni++)
                    acc[mi][ni] = __builtin_amdgcn_mfma_f32_16x16x32_bf16(
                        af[mi], bf[ni], acc[mi][ni], 0, 0, 0);
        }
        __syncthreads();
    }

    // epilogue: C/D mapping col = lane&15, row = (lane>>4)*4 + i
#pragma unroll
    for (int ni = 0; ni < 4; ni++) {
        int col = n0 + wc * 64 + ni * 16 + (lane & 15);
        float bv = bias[col];
#pragma unroll
        for (int mi = 0; mi < 4; mi++) {
            int rbase = m0 + wr * 64 + mi * 16 + ((lane >> 4) << 2);
#pragma unroll
            for (int i = 0; i < 4; i++) {
                out[(size_t)(rbase + i) * VDIM + col] = acc[mi][ni][i] + bv;
            }
        }
    }
}

extern "C" void kernel_launch(void* const* d_in, const int* in_sizes, int n_in,
                              void* d_out, int out_size, void* d_ws, size_t ws_size,
                              hipStream_t stream) {
    const float* src  = (const float*)d_in[0];
    const int*   slen = (const int*)d_in[1];
    const float* tgt  = (const float*)d_in[2];
    const int*   tlen = (const int*)d_in[3];
    const float* W    = (const float*)d_in[4];
    const float* bias = (const float*)d_in[5];
    float* out = (float*)d_out;

    unsigned short* act = (unsigned short*)d_ws;                       // 134,217,728 B
    unsigned short* Wb  = (unsigned short*)((char*)d_ws + OUT_MAIN);   // 1,048,576 B

    prep_act<<<32768, 256, 0, stream>>>(src, tgt, act);
    prep_w<<<256, 256, 0, stream>>>(W, Wb, slen, tlen, out + OUT_MAIN);
    gemm_bf16<<<8192, 256, 0, stream>>>(act, Wb, bias, out);
}